// Round 6
// baseline (32.818 us; speedup 1.0000x reference)
//
#include <hip/hip_runtime.h>

// YOLO loss: preds/targets (N,7,7,2*(5+20)) fp32 -> scalar fp32.
// S=7, B=2, C=20, LAMBDA_NOOBJ=0.5, EPS=1e-9, divide by N at the end.
//
// R6: double per-CU stream count. Tile = 32 cells (12.8KB both tensors),
// double-buffered = 25.6KB/block -> 6 blocks/CU (was 3 at 51.2KB). Block =
// 1 wave, zero barriers, counted vmcnt(14) keeps next tile in flight during
// compute (T3/T4). 32 cells / 64 lanes -> each cell split across a lane
// pair: even lane = boxes/IoU/conf, odd lane = 20-class scan; exchange via
// __shfl_xor(,1). Side effect: 32-active-lane ds_reads -> 2-way bank
// aliasing (free) instead of 4-way.
// R3 lesson kept: no same-address atomics (10-18ns each, serial) -- partials
// to d_ws + tiny final kernel. R4 lesson kept: coalesced staging only.

#define NPC 50            // floats per cell per tensor
#define CPT 32            // cells per tile
#define TPB 64            // 1 wave per block
#define TILE_F (CPT * NPC)   // 1600 floats per tensor per tile

typedef const __attribute__((address_space(1))) void gvoid_t;
typedef __attribute__((address_space(3))) void lvoid_t;

__device__ __forceinline__ float iou_xywh(float px, float py, float pw, float ph,
                                          float tx, float ty, float tw, float th) {
    float ax1 = px - pw * 0.5f, ay1 = py - ph * 0.5f;
    float ax2 = px + pw * 0.5f, ay2 = py + ph * 0.5f;
    float bx1 = tx - tw * 0.5f, by1 = ty - th * 0.5f;
    float bx2 = tx + tw * 0.5f, by2 = ty + th * 0.5f;
    float iw = fmaxf(fminf(ax2, bx2) - fmaxf(ax1, bx1), 0.0f);
    float ih = fmaxf(fminf(ay2, by2) - fmaxf(ay1, by1), 0.0f);
    float inter = iw * ih;
    float uni = pw * ph + tw * th - inter;
    return inter / (uni + 1e-9f);
}

// Full per-cell loss (1 lane per cell) -- used only on the remainder path.
__device__ __forceinline__ float cell_loss(const float2* __restrict__ cp2,
                                           const float2* __restrict__ ct2) {
    float2 p01 = cp2[0], p23 = cp2[1];
    float2 t01 = ct2[0], t23 = ct2[1], t4_ = ct2[2];
    float2 pA = cp2[12], pB = cp2[13], pC = cp2[14];
    float2 tA = ct2[12], tB = ct2[13], tC = ct2[14];

    float iou0 = iou_xywh(p01.x, p01.y, p23.x, p23.y, t01.x, t01.y, t23.x, t23.y);
    float iou1 = iou_xywh(pA.y, pB.x, pB.y, pC.x, tA.y, tB.x, tB.y, tC.x);
    int best = (iou1 > iou0) ? 1 : 0;
    bool has_obj = (t4_.x > 0.0f) || (tC.y > 0.0f);

    float dx, dy;
    if (best == 0) { dx = p01.x - t01.x; dy = p01.y - t01.y; }
    else           { dx = pA.y - tA.y;   dy = pB.x - tB.x;   }
    float cell = has_obj ? (dx * dx + dy * dy) : 0.0f;

    float csum = 0.0f, bv = -1e30f, pg = 0.0f;
    #pragma unroll
    for (int j = 0; j < 10; ++j) {
        float2 tv = ct2[15 + j];
        float2 pv = cp2[15 + j];
        float d0 = pv.x - tv.x, d1 = pv.y - tv.y;
        csum += d0 * d0 + d1 * d1;
        if (tv.x > bv) { bv = tv.x; pg = pv.x; }
        if (tv.y > bv) { bv = tv.y; pg = pv.y; }
    }
    cell += csum;

    float f = pg - 1.0f, f2 = f * f;
    float e0 = iou0 * iou0 * f2, e1 = iou1 * iou1 * f2;
    cell += (best == 0) ? e0 : 0.5f * e0;
    cell += (best == 1) ? e1 : 0.5f * e1;
    return cell;
}

__global__ __launch_bounds__(TPB) void yolo_cell_kernel(
        const float* __restrict__ preds,
        const float* __restrict__ targets,
        float* __restrict__ part,
        int ncells, int nb) {
    __shared__ float lbuf[2][2 * TILE_F];   // [buf][preds|targets] = 25.6 KB

    const int lane = threadIdx.x;           // 0..63
    const int odd = lane & 1;
    const int c = lane >> 1;                // cell 0..31, shared by lane pair
    const int bid = blockIdx.x;
    const int ntiles = ncells / CPT;

    float acc = 0.0f;

    // Stage one 32-cell tile (both tensors): per tensor 6x w16 + 1x w4.
    // Linear LDS (global_load_lds writes base + lane*width). 14 loads total.
    auto stage = [&](int b, int t) {
        const float* ps = preds + (long long)t * TILE_F;
        const float* ts = targets + (long long)t * TILE_F;
        float* lp = lbuf[b];
        float* lt = lbuf[b] + TILE_F;
        #pragma unroll
        for (int k = 0; k < 6; ++k)
            __builtin_amdgcn_global_load_lds((gvoid_t*)(ps + k * 256 + lane * 4),
                                             (lvoid_t*)(lp + k * 256), 16, 0, 0);
        __builtin_amdgcn_global_load_lds((gvoid_t*)(ps + 1536 + lane),
                                         (lvoid_t*)(lp + 1536), 4, 0, 0);
        #pragma unroll
        for (int k = 0; k < 6; ++k)
            __builtin_amdgcn_global_load_lds((gvoid_t*)(ts + k * 256 + lane * 4),
                                             (lvoid_t*)(lt + k * 256), 16, 0, 0);
        __builtin_amdgcn_global_load_lds((gvoid_t*)(ts + 1536 + lane),
                                         (lvoid_t*)(lt + 1536), 4, 0, 0);
    };

    // ---- software pipeline: prologue stage, counted-vmcnt steady state ----
    if (bid < ntiles) stage(0, bid);
    int b = 0;
    for (int t = bid; t < ntiles; t += nb) {
        const int tn = t + nb;
        if (tn < ntiles) {
            stage(b ^ 1, tn);
            // wait only for tile t's 14 loads; tn's 14 stay in flight
            asm volatile("s_waitcnt vmcnt(14)" ::: "memory");
        } else {
            asm volatile("s_waitcnt vmcnt(0)" ::: "memory");
        }
        __builtin_amdgcn_sched_barrier(0);

        const float2* cp2 = (const float2*)(lbuf[b] + c * NPC);
        const float2* ct2 = (const float2*)(lbuf[b] + TILE_F + c * NPC);

        // lane pair splits one cell: even = boxes/IoU/conf, odd = class scan
        float iou0 = 0.0f, iou1 = 0.0f, dxy = 0.0f;
        int best = 0;
        bool has_obj = false;
        float csum = 0.0f, pg = 0.0f;
        if (!odd) {
            float2 p01 = cp2[0], p23 = cp2[1];
            float2 t01 = ct2[0], t23 = ct2[1], t4_ = ct2[2];
            float2 pA = cp2[12], pB = cp2[13], pC = cp2[14];
            float2 tA = ct2[12], tB = ct2[13], tC = ct2[14];
            iou0 = iou_xywh(p01.x, p01.y, p23.x, p23.y,
                            t01.x, t01.y, t23.x, t23.y);
            iou1 = iou_xywh(pA.y, pB.x, pB.y, pC.x,
                            tA.y, tB.x, tB.y, tC.x);
            best = (iou1 > iou0) ? 1 : 0;
            has_obj = (t4_.x > 0.0f) || (tC.y > 0.0f);
            float dx, dy;
            if (best == 0) { dx = p01.x - t01.x; dy = p01.y - t01.y; }
            else           { dx = pA.y - tA.y;   dy = pB.x - tB.x;   }
            dxy = dx * dx + dy * dy;
        } else {
            float bv = -1e30f;
            #pragma unroll
            for (int j = 0; j < 10; ++j) {
                float2 tv = ct2[15 + j];
                float2 pv = cp2[15 + j];
                float d0 = pv.x - tv.x, d1 = pv.y - tv.y;
                csum += d0 * d0 + d1 * d1;
                if (tv.x > bv) { bv = tv.x; pg = pv.x; }
                if (tv.y > bv) { bv = tv.y; pg = pv.y; }
            }
        }
        float pgx = __shfl_xor(pg, 1);    // even lane receives odd's p_gt
        float csx = __shfl_xor(csum, 1);  // even lane receives odd's class MSE
        if (!odd) {
            float cell = (has_obj ? dxy : 0.0f) + csx;
            float f = pgx - 1.0f, f2 = f * f;
            float e0 = iou0 * iou0 * f2, e1 = iou1 * iou1 * f2;
            cell += (best == 0) ? e0 : 0.5f * e0;
            cell += (best == 1) ? e1 : 0.5f * e1;
            acc += cell;
        }
        b ^= 1;
    }

    // ---- remainder cells (ncells % 32; zero for this problem size) ----
    const int rem0 = ntiles * CPT;
    if (rem0 < ncells && bid == nb - 1) {
        for (int i = rem0 + lane; i < ncells; i += TPB) {
            const float2* cp2 = (const float2*)(preds + (long long)i * NPC);
            const float2* ct2 = (const float2*)(targets + (long long)i * NPC);
            acc += cell_loss(cp2, ct2);
        }
    }

    // ---- wave reduction, one plain store per block (no atomics) ----
    #pragma unroll
    for (int off = 32; off >= 1; off >>= 1) acc += __shfl_down(acc, off);
    if (lane == 0) part[bid] = acc;
}

__global__ __launch_bounds__(256) void yolo_final_kernel(
        const float* __restrict__ part, float* __restrict__ out,
        int nblk, float invN) {
    __shared__ float wsum[4];
    const int tid = threadIdx.x;
    float s = 0.0f;
    for (int i = tid; i < nblk; i += 256) s += part[i];
    #pragma unroll
    for (int off = 32; off >= 1; off >>= 1) s += __shfl_down(s, off);
    if ((tid & 63) == 0) wsum[tid >> 6] = s;
    __syncthreads();
    if (tid == 0) {
        out[0] = (wsum[0] + wsum[1] + wsum[2] + wsum[3]) * invN;
    }
}

extern "C" void kernel_launch(void* const* d_in, const int* in_sizes, int n_in,
                              void* d_out, int out_size, void* d_ws, size_t ws_size,
                              hipStream_t stream) {
    const float* preds = (const float*)d_in[0];
    const float* targets = (const float*)d_in[1];
    float* out = (float*)d_out;
    float* part = (float*)d_ws;                 // nb floats of scratch

    const int ncells = in_sizes[0] / NPC;       // N*S*S = 401408
    const int N = ncells / 49;                  // S*S = 49
    const int nb = 1536;                         // 6 blocks/CU x 256 CU

    yolo_cell_kernel<<<nb, TPB, 0, stream>>>(preds, targets, part, ncells, nb);
    yolo_final_kernel<<<1, 256, 0, stream>>>(part, out, nb, 1.0f / (float)N);
}